// Round 1
// 110.850 us; speedup vs baseline: 1.0174x; 1.0174x over previous
//
#include <hip/hip_runtime.h>
#include <stdint.h>

#define B_ROWS 1024
#define FEAT   256
#define QSZ    32768
#define SHIFT  1024
#define QX     (QSZ - B_ROWS)   // 31744
#define NQB    256              // q-tiles of 128 (M dim of GEMM)
#define NXB    8                // x-tiles of 128 (N dim)
#define MARGIN 8.0f             // covers bf16 noise (~2) + key quantization (~2.5/side)

typedef float  v4f __attribute__((ext_vector_type(4)));
typedef short  v8s __attribute__((ext_vector_type(8)));

// ---------- packed score keys: orderable(m)[31:15] | j[14:0] ----------
__device__ __forceinline__ uint32_t key_flip(uint32_t u) {
    return u ^ ((uint32_t)((int32_t)u >> 31) | 0x80000000u);
}
__device__ __forceinline__ float key_m(uint32_t k) {  // floor-approx m back from key
    uint32_t u = k & 0xFFFF8000u;
    u = (u & 0x80000000u) ? (u ^ 0x80000000u) : ~u;
    return __uint_as_float(u);
}
// sorted-pair top2 insert / merge (branchless)
__device__ __forceinline__ void k2_insert(uint32_t& k1, uint32_t& k2, uint32_t key) {
    uint32_t hi = max(k1, key); k1 = min(k1, key); k2 = min(k2, hi);
}
__device__ __forceinline__ uint2 k2_merge(uint2 a, uint2 b) {
    uint32_t hi = max(a.x, b.x);
    uint2 r; r.x = min(a.x, b.x); r.y = min(min(a.y, b.y), hi);
    return r;
}

// ---------- exact-score top2 (float + index tie-break, matches top_k) ----------
struct Top2 { float m1; int j1; float m2; int j2; };
__device__ __forceinline__ bool better(float ma, int ja, float mb, int jb) {
    return (ma < mb) || (ma == mb && ja < jb);
}
__device__ __forceinline__ void t2_insert(Top2& t, float m, int j) {
    if (better(m, j, t.m1, t.j1)) { t.m2 = t.m1; t.j2 = t.j1; t.m1 = m; t.j1 = j; }
    else if (better(m, j, t.m2, t.j2)) { t.m2 = m; t.j2 = j; }
}

__device__ __forceinline__ const float* q_row_ptr(int j, const float* x, const float* queue) {
    return (j < QX) ? (queue + (size_t)(j + SHIFT) * FEAT) : (x + (size_t)(j - QX) * FEAT);
}

__device__ __forceinline__ unsigned short f2bf(float f) {  // round-to-nearest-even
    uint32_t u = __float_as_uint(f);
    uint32_t r = u + 0x7FFFu + ((u >> 16) & 1u);
    return (unsigned short)(r >> 16);
}

__device__ __forceinline__ void lds_load16(const void* g, void* l) {
    __builtin_amdgcn_global_load_lds(
        (const __attribute__((address_space(1))) uint32_t*)g,
        (__attribute__((address_space(3))) uint32_t*)l, 16, 0, 0);
}

// ---------- kernel 1: q_bf (bf16 row-major, x tail included) + q2 (f32) ----------
__global__ __launch_bounds__(256) void convert_kernel(const float* __restrict__ x,
                                                      const float* __restrict__ queue,
                                                      unsigned short* __restrict__ q_bf,
                                                      float* __restrict__ q2) {
    int wave = threadIdx.x >> 6, lane = threadIdx.x & 63;
    int j = blockIdx.x * 4 + wave;
    const float4* row = (const float4*)q_row_ptr(j, x, queue);
    float4 v = row[lane];
    float s = v.x * v.x + v.y * v.y + v.z * v.z + v.w * v.w;
#pragma unroll
    for (int off = 32; off; off >>= 1) s += __shfl_xor(s, off, 64);
    if (lane == 0) q2[j] = s;
    ushort4 h;
    h.x = f2bf(v.x); h.y = f2bf(v.y); h.z = f2bf(v.z); h.w = f2bf(v.w);
    ((ushort4*)q_bf)[(size_t)j * 64 + lane] = h;
}

// ---------- kernel 2: MFMA GEMM, A=q rows (M), B=x rows (N); packed-key top2 per x-col ----------
// v2: depth-2 pipelined 8-phase K-loop (32-feat chunks, double-buffered LDS,
//     counted vmcnt(4) + raw s_barrier so prefetch stays in flight across the
//     barrier — m201/T3+T4 pattern), XCD-pinned block mapping (each XCD owns a
//     contiguous 32-gy stripe so its 2 MB of A stays L2-resident), s_setprio
//     around the MFMA cluster (T5).
__device__ __forceinline__ void stage_chunk(const unsigned short* gA, const unsigned short* gB,
                                            unsigned short* asb, unsigned short* bsb,
                                            int w, int c) {
    // per wave: rows [w*32, w*32+32) of the 128-row tile, 64B (32 feats) per row.
    // lane l: row (l>>2) within each 16-row group, source granule pre-swizzled so
    // phys slot (l&3) stores logical granule (l&3)^((row>>1)&3)  (read-side XOR).
    lds_load16(gA + (size_t)c * 32,             asb + (w * 32) * 32);
    lds_load16(gA + (size_t)c * 32 + 16 * FEAT, asb + (w * 32 + 16) * 32);
    lds_load16(gB + (size_t)c * 32,             bsb + (w * 32) * 32);
    lds_load16(gB + (size_t)c * 32 + 16 * FEAT, bsb + (w * 32 + 16) * 32);
}

__global__ __launch_bounds__(256, 3) void nn_mfma(const unsigned short* __restrict__ q_bf,
                                                  const float* __restrict__ q2,
                                                  uint2* __restrict__ partials) {
    __shared__ unsigned short As[2][128 * 32];  // 8 KB per buf, q-tile chunk
    __shared__ unsigned short Bs[2][128 * 32];  // 8 KB per buf, x-tile chunk
    __shared__ uint2 scr[128][2];               // cross-wm merge scratch (2 KB)

    const int t    = threadIdx.x;
    const int w    = t >> 6, lane = t & 63;
    const int wm   = w >> 1, wn = w & 1;
    const int quad = lane >> 4, l16 = lane & 15;

    // XCD-pinned bijective swizzle: block p -> XCD p&7 (round-robin heuristic).
    // XCD x handles gy in [32x, 32x+32), gx fastest within -> A stripe (2 MB)
    // + full B (512 KB) resident in that XCD's 4 MB L2.
    const int p  = blockIdx.x;
    const int gy = (p & 7) * 32 + (p >> 6);  // q tile (rows of D)
    const int gx = (p >> 3) & 7;             // x tile (cols of D)

    const unsigned short* x_bf = q_bf + (size_t)QX * FEAT;

    // staging lane decomposition (16 rows x 4 granules of 16B per instr)
    const int srow = lane >> 2;                        // row within 16-row group
    const int sgl  = (lane & 3) ^ ((lane >> 3) & 3);   // pre-swizzled source granule
    const unsigned short* gA = q_bf + (size_t)(gy * 128 + w * 32 + srow) * FEAT + sgl * 8;
    const unsigned short* gB = x_bf + (size_t)(gx * 128 + w * 32 + srow) * FEAT + sgl * 8;

    v4f acc[4][4];  // [tm: q sub-rows][tn: x sub-cols]
#pragma unroll
    for (int a = 0; a < 4; ++a)
#pragma unroll
        for (int b = 0; b < 4; ++b) acc[a][b] = (v4f)0.0f;

    // read-side fragment base: row (wm*64 + tm*16 + l16), phys granule quad^((l16>>1)&3)
    const int gphys = quad ^ ((l16 >> 1) & 3);
    const char* Ard = (const char*)&As[0][0] + (size_t)(wm * 64 + l16) * 64 + gphys * 16;
    const char* Brd = (const char*)&Bs[0][0] + (size_t)(wn * 64 + l16) * 64 + gphys * 16;

    stage_chunk(gA, gB, As[0], Bs[0], w, 0);  // prologue: chunk 0 -> buf 0

#pragma unroll
    for (int c = 0; c < 8; ++c) {
        if (c < 7) stage_chunk(gA, gB, As[(c + 1) & 1], Bs[(c + 1) & 1], w, c + 1);
        __builtin_amdgcn_sched_barrier(0);  // pin prefetch issues before the counted wait
        if (c < 7) asm volatile("s_waitcnt vmcnt(4)" ::: "memory");  // stage(c) done, stage(c+1) in flight
        else       asm volatile("s_waitcnt vmcnt(0)" ::: "memory");
        __builtin_amdgcn_s_barrier();       // raw: does NOT drain the in-flight prefetch

        const char* Ac = Ard + (c & 1) * 8192;
        const char* Bc = Brd + (c & 1) * 8192;
        v8s fa[4], fb[4];
#pragma unroll
        for (int tm = 0; tm < 4; ++tm) fa[tm] = *(const v8s*)(Ac + tm * 1024);
#pragma unroll
        for (int tn = 0; tn < 4; ++tn) fb[tn] = *(const v8s*)(Bc + tn * 1024);
        __builtin_amdgcn_s_setprio(1);
#pragma unroll
        for (int tm = 0; tm < 4; ++tm)
#pragma unroll
            for (int tn = 0; tn < 4; ++tn)
                acc[tm][tn] = __builtin_amdgcn_mfma_f32_16x16x32_bf16(fa[tm], fb[tn], acc[tm][tn], 0, 0, 0);
        __builtin_amdgcn_s_setprio(0);
        __builtin_amdgcn_s_barrier();       // close reads of buf (c&1) before it is restaged
    }

    // ---- epilogue: keys = orderable(q2[row]-2*acc)|row; per-thread top2 per x-col ----
    float q2r[4][4];
#pragma unroll
    for (int tm = 0; tm < 4; ++tm) {
        v4f qq = *(const v4f*)(q2 + gy * 128 + wm * 64 + tm * 16 + quad * 4);
#pragma unroll
        for (int r = 0; r < 4; ++r) q2r[tm][r] = qq[r];
    }
    const int jbase = gy * 128 + wm * 64 + quad * 4;

    uint2 best[4];
#pragma unroll
    for (int tn = 0; tn < 4; ++tn) {
        uint32_t k1 = 0xFFFFFFFFu, k2 = 0xFFFFFFFFu;
#pragma unroll
        for (int tm = 0; tm < 4; ++tm)
#pragma unroll
            for (int r = 0; r < 4; ++r) {
                float m = fmaf(-2.0f, acc[tm][tn][r], q2r[tm][r]);
                uint32_t u = key_flip(__float_as_uint(m));
                uint32_t key = (u & 0xFFFF8000u) | (uint32_t)(jbase + tm * 16 + r);
                k2_insert(k1, k2, key);
            }
        // merge across quads (same x-col lives in lanes l16, l16+16, l16+32, l16+48)
#pragma unroll
        for (int mask = 16; mask <= 32; mask <<= 1) {
            uint32_t o1 = __shfl_xor(k1, mask, 64);
            uint32_t o2 = __shfl_xor(k2, mask, 64);
            uint32_t hi = max(k1, o1);
            k1 = min(k1, o1);
            k2 = min(min(k2, o2), hi);
        }
        best[tn] = make_uint2(k1, k2);
    }
    if (quad == 0) {
#pragma unroll
        for (int tn = 0; tn < 4; ++tn) scr[wn * 64 + tn * 16 + l16][wm] = best[tn];
    }
    __syncthreads();
    if (t < 128) {
        uint2 r = k2_merge(scr[t][0], scr[t][1]);
        partials[(size_t)(gx * 128 + t) * NQB + gy] = r;
    }
}

// ---------- kernel 3: key-based cutoff + exact f32 rescore + gather ----------
__global__ __launch_bounds__(256) void nn_finalize(const float* __restrict__ x,
                                                   const float* __restrict__ queue,
                                                   const float* __restrict__ q2,
                                                   const uint2* __restrict__ partials,
                                                   float* __restrict__ out) {
    __shared__ float    xs[256];
    __shared__ uint2    red[256];
    __shared__ int      list[64];
    __shared__ float    escore[64];
    __shared__ int      s_cnt;
    __shared__ uint32_t s_kcut;
    __shared__ int      s_j2;

    const int t = threadIdx.x, i = blockIdx.x;
    const int w = t >> 6, lane = t & 63;

    xs[t] = x[(size_t)i * FEAT + t];
    uint2 p = partials[(size_t)i * NQB + t];
    red[t] = p;
    if (t == 0) s_cnt = 0;
    __syncthreads();

    if (w == 0) {  // approx global top2 (keys) -> cutoff key
        uint2 a = red[lane];
        a = k2_merge(a, red[lane + 64]);
        a = k2_merge(a, red[lane + 128]);
        a = k2_merge(a, red[lane + 192]);
#pragma unroll
        for (int mask = 1; mask <= 32; mask <<= 1) {
            uint2 o;
            o.x = __shfl_xor(a.x, mask, 64);
            o.y = __shfl_xor(a.y, mask, 64);
            a = k2_merge(a, o);
        }
        if (lane == 0) {
            float cutf = key_m(a.y) + MARGIN;
            s_kcut = key_flip(__float_as_uint(cutf)) | 0x7FFFu;
        }
    }
    __syncthreads();
    uint32_t kcut = s_kcut;
    if (p.x <= kcut) { int q_ = atomicAdd(&s_cnt, 1); if (q_ < 64) list[q_] = (int)(p.x & 0x7FFFu); }
    if (p.y <= kcut) { int q_ = atomicAdd(&s_cnt, 1); if (q_ < 64) list[q_] = (int)(p.y & 0x7FFFu); }
    __syncthreads();
    int n = min(s_cnt, 64);

    for (int c = w; c < n; c += 4) {  // exact f32 rescore, one candidate per wave
        int j = list[c];
        const float4* qr = (const float4*)q_row_ptr(j, x, queue);
        float4 qv = qr[lane];
        float4 xv = ((const float4*)xs)[lane];
        float s = qv.x * xv.x + qv.y * xv.y + qv.z * xv.z + qv.w * xv.w;
#pragma unroll
        for (int off = 32; off; off >>= 1) s += __shfl_xor(s, off, 64);
        if (lane == 0) escore[c] = q2[j] - 2.0f * s;
    }
    __syncthreads();
    if (t == 0) {
        Top2 a;
        a.m1 = __builtin_inff(); a.j1 = 0x7FFFFFFF;
        a.m2 = __builtin_inff(); a.j2 = 0x7FFFFFFF;
        for (int c = 0; c < n; ++c) t2_insert(a, escore[c], list[c]);
        s_j2 = a.j2;  // second-nearest (nearest is self)
    }
    __syncthreads();
    out[(size_t)i * FEAT + t] = q_row_ptr(s_j2, x, queue)[t];
}

extern "C" void kernel_launch(void* const* d_in, const int* in_sizes, int n_in,
                              void* d_out, int out_size, void* d_ws, size_t ws_size,
                              hipStream_t stream) {
    const float* x     = (const float*)d_in[0];
    const float* queue = (const float*)d_in[1];

    unsigned short* q_bf     = (unsigned short*)d_ws;                    // 16 MB
    float*          q2       = (float*)((char*)d_ws + (16u << 20));      // 128 KB
    uint2*          partials = (uint2*)((char*)d_ws + (17u << 20));      // 2 MB

    convert_kernel<<<QSZ / 4, 256, 0, stream>>>(x, queue, q_bf, q2);
    nn_mfma<<<NQB * NXB, 256, 0, stream>>>(q_bf, q2, partials);
    nn_finalize<<<B_ROWS, 256, 0, stream>>>(x, queue, q2, partials, (float*)d_out);
}